// Round 15
// baseline (178.713 us; speedup 1.0000x reference)
//
#include <hip/hip_runtime.h>
#include <hip/hip_fp16.h>

#define N_NODES 50000
#define N_EDGES 800000
// D_FEAT=64, D_EDGE=16, D_HID=16, D_MSG=64, D_OUT=64

#define NB   196    // coarse buckets of 256 nodes (196*256 = 50176)
#define PB   256    // chist/part1 blocks
#define EPB  3125   // edges per block (256*3125 = 800000 exact)
#define PIT  13     // ceil(3125/256)
#define CAP2 4608   // part2 LDS stage capacity (mean 4081, +8 sigma)
#define NVT  50176  // padded node count

__device__ __forceinline__ unsigned fkey(float f) {
    unsigned u = __float_as_uint(f);
    return (u & 0x80000000u) ? ~u : (u | 0x80000000u);
}
#define KEY_NEG_INF 0x007FFFFFu

__device__ __forceinline__ void wave_lds_fence() {
    asm volatile("s_waitcnt lgkmcnt(0)" ::: "memory");
    __builtin_amdgcn_sched_barrier(0);
}

// block-wide exclusive scan of 256 values (one per thread). Uniform call only.
__device__ __forceinline__ unsigned block_exscan256(unsigned v, unsigned* wsum,
                                                    unsigned* chunkTot) {
    const int t = threadIdx.x, lane = t & 63, w = t >> 6;
    unsigned inc = v;
#pragma unroll
    for (int d = 1; d < 64; d <<= 1) {
        unsigned n = __shfl_up(inc, d, 64);
        if (lane >= d) inc += n;
    }
    if (lane == 63) wsum[w] = inc;
    __syncthreads();
    unsigned woff = 0;
#pragma unroll
    for (int i = 0; i < 3; ++i) if (i < w) woff += wsum[i];
    if (chunkTot && t == 255) *chunkTot = woff + inc;
    __syncthreads();
    return woff + inc - v;
}

// ---------------- chist + xw ------------------------------------------------
__global__ __launch_bounds__(256) void chist_xw_kernel(
    const int* __restrict__ dst, unsigned* __restrict__ bcnt,
    const float* __restrict__ x, const float* __restrict__ W1,
    const float* __restrict__ b1, float* __restrict__ xw)
{
    __shared__ unsigned lh[NB];
    const int t = threadIdx.x, b = blockIdx.x;
    if (t < NB) lh[t] = 0u;
    __syncthreads();
    const int e0 = b * EPB;
#pragma unroll
    for (int it = 0; it < PIT; ++it) {
        const int i = it * 256 + t;
        if (i < EPB) atomicAdd(&lh[(unsigned)dst[e0 + i] >> 8], 1u);
    }
    __syncthreads();
    if (t < NB) bcnt[(size_t)b * NB + t] = lh[t];

    if (b < 196) {
        const int v = b * 256 + t;
        if (v < N_NODES) {
            float acc[16];
#pragma unroll
            for (int k = 0; k < 16; ++k) acc[k] = b1[k];
            const float4* xp = reinterpret_cast<const float4*>(x) + (size_t)v * 16;
#pragma unroll
            for (int c = 0; c < 16; ++c) {
                float4 tv = xp[c];
                const float xv[4] = {tv.x, tv.y, tv.z, tv.w};
#pragma unroll
                for (int q = 0; q < 4; ++q) {
                    const int row = 16 + 4 * c + q;
#pragma unroll
                    for (int k = 0; k < 16; ++k)
                        acc[k] = fmaf(xv[q], W1[row * 16 + k], acc[k]);
                }
            }
            float4* op = reinterpret_cast<float4*>(xw) + (size_t)v * 4;
#pragma unroll
            for (int c = 0; c < 4; ++c) {
                float4 o; o.x = acc[4*c]; o.y = acc[4*c+1]; o.z = acc[4*c+2]; o.w = acc[4*c+3];
                op[c] = o;
            }
        }
    }
}

// ---------------- cscanA: in-place exscan of each bucket column ------------
__global__ __launch_bounds__(256) void cscanA_kernel(unsigned* __restrict__ bcnt,
                                                     unsigned* __restrict__ tot) {
    __shared__ unsigned wsum[4];
    const int t = threadIdx.x, bu = blockIdx.x;   // PB == 256: one chunk
    const unsigned v = bcnt[(size_t)t * NB + bu];
    const unsigned excl = block_exscan256(v, wsum, nullptr);
    bcnt[(size_t)t * NB + bu] = excl;
    if (t == 255) tot[bu] = excl + v;
}

// ---------------- cscanB: boffG = exscan(tot[196]) -------------------------
__global__ __launch_bounds__(256) void cscanB_kernel(const unsigned* __restrict__ tot,
                                                     unsigned* __restrict__ boffG) {
    __shared__ unsigned wsum[4];
    const int t = threadIdx.x;
    const unsigned v = (t < NB) ? tot[t] : 0u;
    const unsigned excl = block_exscan256(v, wsum, nullptr);
    if (t < NB) boffG[t] = excl;
}

// ---------------- hcomp: h16 + rkey init -----------------------------------
__global__ __launch_bounds__(256) void hcomp_kernel(
    const float* __restrict__ ef, const int* __restrict__ src,
    const float* __restrict__ xw, const float* __restrict__ W1,
    unsigned* __restrict__ rkey, unsigned* __restrict__ h16)
{
    const int e = blockIdx.x * 256 + threadIdx.x;  // 3125*256 = 800000 exact
    reinterpret_cast<uint4*>(rkey)[e] =
        make_uint4(KEY_NEG_INF, KEY_NEG_INF, KEY_NEG_INF, KEY_NEG_INF);

    float in[16];
    const float4* efp = reinterpret_cast<const float4*>(ef) + (size_t)e * 4;
#pragma unroll
    for (int c = 0; c < 4; ++c) {
        float4 tv = efp[c];
        in[4*c+0]=tv.x; in[4*c+1]=tv.y; in[4*c+2]=tv.z; in[4*c+3]=tv.w;
    }
    const int s = src[e];
    float h[16];
    const float4* xp = reinterpret_cast<const float4*>(xw) + (size_t)s * 4;
#pragma unroll
    for (int c = 0; c < 4; ++c) {
        float4 tv = xp[c];
        h[4*c+0]=tv.x; h[4*c+1]=tv.y; h[4*c+2]=tv.z; h[4*c+3]=tv.w;
    }
#pragma unroll
    for (int i = 0; i < 16; ++i)
#pragma unroll
        for (int k = 0; k < 16; ++k)
            h[k] = fmaf(in[i], W1[i*16 + k], h[k]);
    unsigned wds[8];
#pragma unroll
    for (int k = 0; k < 8; ++k) {
        __half2 t2 = __floats2half2_rn(fmaxf(h[2*k], 0.0f), fmaxf(h[2*k+1], 0.0f));
        wds[k] = *reinterpret_cast<unsigned*>(&t2);
    }
    uint4* hp = reinterpret_cast<uint4*>(h16) + (size_t)e * 2;
    hp[0] = make_uint4(wds[0], wds[1], wds[2], wds[3]);
    hp[1] = make_uint4(wds[4], wds[5], wds[6], wds[7]);
}

// ---------------- part1: coarse partition, payload (nloc8<<20)|e -----------
__global__ __launch_bounds__(256) void part1_kernel(
    const int* __restrict__ dst, const unsigned* __restrict__ gstart,
    const unsigned* __restrict__ boffG, unsigned* __restrict__ part1)
{
    __shared__ unsigned stV[EPB];            // 12.5 KB
    __shared__ unsigned char stB[EPB];       // 3.1 KB
    __shared__ unsigned lh[NB], lstart[NB], lc[NB], gs[NB];
    __shared__ unsigned wsum[4];
    const int t = threadIdx.x, b = blockIdx.x;
    if (t < NB) lh[t] = 0u;
    __syncthreads();
    const int e0 = b * EPB;
#pragma unroll
    for (int it = 0; it < PIT; ++it) {
        const int i = it * 256 + t;
        if (i < EPB) atomicAdd(&lh[(unsigned)dst[e0 + i] >> 8], 1u);
    }
    __syncthreads();
    {
        const unsigned v = (t < NB) ? lh[t] : 0u;
        const unsigned excl = block_exscan256(v, wsum, nullptr);
        if (t < NB) {
            lstart[t] = excl;
            lc[t]     = excl;
            gs[t]     = gstart[(size_t)b * NB + t] + boffG[t];
        }
    }
    __syncthreads();
#pragma unroll
    for (int it = 0; it < PIT; ++it) {
        const int i = it * 256 + t;
        if (i < EPB) {
            const int e = e0 + i;
            const unsigned d = (unsigned)dst[e];
            const unsigned bkt = d >> 8;
            const unsigned p = atomicAdd(&lc[bkt], 1u);
            stV[p] = ((d & 255u) << 20) | (unsigned)e;
            stB[p] = (unsigned char)bkt;
        }
    }
    __syncthreads();
#pragma unroll
    for (int it = 0; it < PIT; ++it) {
        const int i = it * 256 + t;
        if (i < EPB) {
            const unsigned bkt = stB[i];
            part1[gs[bkt] + ((unsigned)i - lstart[bkt])] = stV[i];
        }
    }
}

// ---------------- part2: per-node order, emit u64 (dst<<32)|e --------------
__global__ __launch_bounds__(256) void part2_kernel(
    const unsigned* __restrict__ part1,
    const unsigned* __restrict__ boffG, const unsigned* __restrict__ tot,
    unsigned long long* __restrict__ dsf)
{
    __shared__ unsigned long long stE[CAP2];  // 36.9 KB
    __shared__ unsigned fh[256], fstart[256], fcur[256];
    __shared__ unsigned wsum[4];
    const int t = threadIdx.x, b = blockIdx.x;
    const unsigned gb = boffG[b], cnt = tot[b];
    fh[t] = 0u; fcur[t] = 0u;
    __syncthreads();
    const int iters = (int)((cnt + 255u) >> 8);
    for (int it = 0; it < iters; ++it) {
        const unsigned i = (unsigned)it * 256u + (unsigned)t;
        if (i < cnt) atomicAdd(&fh[part1[gb + i] >> 20], 1u);
    }
    __syncthreads();
    {
        const unsigned v = fh[t];
        fstart[t] = block_exscan256(v, wsum, nullptr);
    }
    __syncthreads();
    for (int it = 0; it < iters; ++it) {
        const unsigned i = (unsigned)it * 256u + (unsigned)t;
        if (i < cnt) {
            const unsigned pv = part1[gb + i];
            const unsigned nloc = pv >> 20;
            const unsigned e = pv & 0xFFFFFu;
            const unsigned pos = fstart[nloc] + atomicAdd(&fcur[nloc], 1u);
            const unsigned long long val =
                ((unsigned long long)((unsigned)b * 256u + nloc) << 32) | e;
            if (pos < CAP2) stE[pos] = val;
            else            dsf[gb + pos] = val;   // statistically unreachable
        }
    }
    __syncthreads();
    const unsigned lim = (cnt < CAP2) ? cnt : CAP2;
    for (int it = 0; it < iters; ++it) {
        const unsigned i = (unsigned)it * 256u + (unsigned)t;
        if (i < lim) dsf[gb + i] = stE[i];   // perfectly sequential
    }
}

// ---------------- edge_h16 (r7 verbatim, measured 44.7us) ------------------
__global__ __launch_bounds__(256) void edge_h16_kernel(
    const unsigned* __restrict__ h16,
    const unsigned long long* __restrict__ ds,
    const float* __restrict__ W2, const float* __restrict__ b2,
    unsigned* __restrict__ rkey)
{
    const int lane = threadIdx.x & 63;
    const int w    = threadIdx.x >> 6;
    const int wave = blockIdx.x * 4 + w;
    const int base = wave * 64;
    const int slot = base + lane;

    __shared__ unsigned mld[4][64][17];
    __shared__ int      dldA[4][66];
    int* dld = &dldA[w][1];

    const unsigned long long pv = ds[slot];
    const int e = (int)(unsigned)pv;
    const int d = (int)(pv >> 32);
    dld[lane] = d;
    if (lane == 0)  dld[-1] = (base == 0) ? -1 : (int)(ds[base - 1] >> 32);
    if (lane == 63) dld[64] = (base + 64 >= N_EDGES) ? -1 : (int)(ds[base + 64] >> 32);

    // ---- gather h (32 B random from 25.6 MB) ----
    float h[16];
    {
        const uint4* hp = reinterpret_cast<const uint4*>(h16) + (size_t)e * 2;
        uint4 A = hp[0], B = hp[1];
        unsigned wd[8] = {A.x, A.y, A.z, A.w, B.x, B.y, B.z, B.w};
#pragma unroll
        for (int k = 0; k < 8; ++k) {
            __half2 t2 = *reinterpret_cast<const __half2*>(&wd[k]);
            float2 f = __half22float2(t2);
            h[2*k] = f.x; h[2*k+1] = f.y;
        }
    }

    const int q  = lane >> 4;
    const int jj = lane & 15;

#pragma unroll
    for (int j0 = 0; j0 < 64; j0 += 16) {
        float m[16];
#pragma unroll
        for (int t = 0; t < 16; ++t) m[t] = b2[j0 + t];
#pragma unroll
        for (int k = 0; k < 16; ++k)
#pragma unroll
            for (int t = 0; t < 16; ++t)
                m[t] = fmaf(h[k], W2[k*64 + j0 + t], m[t]);

        wave_lds_fence();
#pragma unroll
        for (int t = 0; t < 16; ++t) mld[w][lane][t] = fkey(m[t]);
        wave_lds_fence();

        const int s0 = q * 16;
        unsigned run = KEY_NEG_INF;
        int  dprev = dld[s0 - 1];
        bool phead = (dld[s0] != dprev);
        dprev = dld[s0];
        run = mld[w][s0][jj];
#pragma unroll
        for (int i = 1; i < 16; ++i) {
            const int ss = s0 + i;
            const int dsv = dld[ss];
            if (dsv != dprev) {
                unsigned* addr = &rkey[((size_t)dprev << 6) + (unsigned)(j0 + jj)];
                if (phead) *addr = run;
                else       atomicMax(addr, run);
                run = KEY_NEG_INF;
                phead = true;
            }
            run = max(run, mld[w][ss][jj]);
            dprev = dsv;
        }
        const bool ptail = (dld[s0 + 16] != dprev);
        unsigned* addr = &rkey[((size_t)dprev << 6) + (unsigned)(j0 + jj)];
        if (phead && ptail) *addr = run;
        else                atomicMax(addr, run);
    }
}

// ---------------- node4: 4 threads/node, coalesced IO, shfl-reduce ---------
// Old node_kernel was 45.5us: 196 blocks (<1/CU, no latency hiding) and
// 256B-stride partial-line stores (WRITE_SIZE 50MB for a 12.8MB output).
// Here: 64 nodes/block x 4 lanes; lane q owns rows [q*16,+16) of x and r,
// partial h2, 2-step shfl_xor butterfly, writes cols [q*16,+16) -> each
// 4-lane group stores one contiguous 256B burst. Grid 784.
// rkey/out alias d_out: each group reads only its node's row before writing.
__global__ __launch_bounds__(256) void node4_kernel(
    const float* __restrict__ x, const unsigned* rkey,
    const float* __restrict__ W1, const float* __restrict__ b1,
    const float* __restrict__ W2, const float* __restrict__ b2,
    float* out)
{
    const int tid = threadIdx.x;
    const int g = tid >> 2;        // node within block, 0..63
    const int q = tid & 3;         // quarter
    const int v = blockIdx.x * 64 + g;
    if (v >= N_NODES) return;      // whole 4-lane group exits together

    // x rows [q*16, q*16+16)
    float xv[16];
    const float4* xp = reinterpret_cast<const float4*>(x) + (size_t)v * 16 + q * 4;
#pragma unroll
    for (int c = 0; c < 4; ++c) {
        float4 tv = xp[c];
        xv[4*c+0]=tv.x; xv[4*c+1]=tv.y; xv[4*c+2]=tv.z; xv[4*c+3]=tv.w;
    }
    // r rows [q*16, q*16+16) decoded from rkey
    float rv[16];
    const uint4* rp = reinterpret_cast<const uint4*>(rkey) + (size_t)v * 16 + q * 4;
#pragma unroll
    for (int c = 0; c < 4; ++c) {
        uint4 tv = rp[c];
        unsigned ks[4] = {tv.x, tv.y, tv.z, tv.w};
#pragma unroll
        for (int qq = 0; qq < 4; ++qq) {
            unsigned k = ks[qq];
            unsigned u = (k & 0x80000000u) ? (k ^ 0x80000000u) : ~k;
            float f = __uint_as_float(u);
            if (!(f >= -3.402823466e38f && f <= 3.402823466e38f)) f = 0.0f;
            rv[4*c + qq] = f;
        }
    }

    // partial h2 over this lane's 32 rows
    float h2[16];
#pragma unroll
    for (int k = 0; k < 16; ++k) h2[k] = 0.0f;
#pragma unroll
    for (int rr = 0; rr < 16; ++rr) {
        const int row = q * 16 + rr;
#pragma unroll
        for (int k = 0; k < 16; ++k)
            h2[k] = fmaf(xv[rr], W1[row * 16 + k], h2[k]);
    }
#pragma unroll
    for (int rr = 0; rr < 16; ++rr) {
        const int row = 64 + q * 16 + rr;
#pragma unroll
        for (int k = 0; k < 16; ++k)
            h2[k] = fmaf(rv[rr], W1[row * 16 + k], h2[k]);
    }
    // butterfly over the 4-lane group (masks 1,2 stay within group)
#pragma unroll
    for (int mk = 1; mk <= 2; mk <<= 1)
#pragma unroll
        for (int k = 0; k < 16; ++k)
            h2[k] += __shfl_xor(h2[k], mk, 64);
#pragma unroll
    for (int k = 0; k < 16; ++k) h2[k] = fmaxf(h2[k] + b1[k], 0.0f);

    // out cols [q*16, +16): 4-lane group writes 256B contiguous
    float* op = out + (size_t)v * 64 + q * 16;
#pragma unroll
    for (int c = 0; c < 4; ++c) {
        float oo[4];
#pragma unroll
        for (int u4 = 0; u4 < 4; ++u4) {
            const int col = q * 16 + 4 * c + u4;
            float a = b2[col];
#pragma unroll
            for (int k = 0; k < 16; ++k)
                a = fmaf(h2[k], W2[k * 64 + col], a);
            oo[u4] = a;
        }
        float4 o; o.x=oo[0]; o.y=oo[1]; o.z=oo[2]; o.w=oo[3];
        reinterpret_cast<float4*>(op)[c] = o;
    }
}

// =================== fallback tier (tiny ws): direct atomics ===============
__global__ __launch_bounds__(256) void init0_kernel(unsigned* __restrict__ rkey) {
    const int i = blockIdx.x * 256 + threadIdx.x;
    reinterpret_cast<uint4*>(rkey)[i] =
        make_uint4(KEY_NEG_INF, KEY_NEG_INF, KEY_NEG_INF, KEY_NEG_INF);
}

__global__ __launch_bounds__(64) void edge_kernel(
    const float* __restrict__ x, const float* __restrict__ ef,
    const int* __restrict__ src, const int* __restrict__ dst,
    const float* __restrict__ W1, const float* __restrict__ b1,
    const float* __restrict__ W2, const float* __restrict__ b2,
    unsigned* __restrict__ rkey)
{
    const int lane = threadIdx.x;
    const int e    = blockIdx.x * 64 + lane;
    __shared__ unsigned mld[64][17];
    __shared__ int      dld[64];
    float in[80];
    const float4* efp = reinterpret_cast<const float4*>(ef) + (size_t)e * 4;
#pragma unroll
    for (int c = 0; c < 4; ++c) {
        float4 tv = efp[c];
        in[4*c+0]=tv.x; in[4*c+1]=tv.y; in[4*c+2]=tv.z; in[4*c+3]=tv.w;
    }
    const int s = src[e];
    dld[lane] = dst[e];
    const float4* xp = reinterpret_cast<const float4*>(x) + (size_t)s * 16;
#pragma unroll
    for (int c = 0; c < 16; ++c) {
        float4 tv = xp[c];
        in[16+4*c+0]=tv.x; in[16+4*c+1]=tv.y; in[16+4*c+2]=tv.z; in[16+4*c+3]=tv.w;
    }
    float h[16];
#pragma unroll
    for (int k = 0; k < 16; ++k) h[k] = b1[k];
#pragma unroll
    for (int i = 0; i < 80; ++i)
#pragma unroll
        for (int k = 0; k < 16; ++k)
            h[k] = fmaf(in[i], W1[i*16 + k], h[k]);
#pragma unroll
    for (int k = 0; k < 16; ++k) h[k] = fmaxf(h[k], 0.0f);
    const int er = lane >> 4, jj = lane & 15;
#pragma unroll
    for (int j0 = 0; j0 < 64; j0 += 16) {
        float m[16];
#pragma unroll
        for (int t = 0; t < 16; ++t) m[t] = b2[j0 + t];
#pragma unroll
        for (int k = 0; k < 16; ++k)
#pragma unroll
            for (int t = 0; t < 16; ++t)
                m[t] = fmaf(h[k], W2[k*64 + j0 + t], m[t]);
        wave_lds_fence();
#pragma unroll
        for (int t = 0; t < 16; ++t) mld[lane][t] = fkey(m[t]);
        wave_lds_fence();
#pragma unroll
        for (int eg = 0; eg < 16; ++eg) {
            const int ee = (eg << 2) | er;
            atomicMax(&rkey[((size_t)dld[ee] << 6) + (unsigned)(j0 + jj)],
                      mld[ee][jj]);
        }
    }
}

extern "C" void kernel_launch(void* const* d_in, const int* in_sizes, int n_in,
                              void* d_out, int out_size, void* d_ws, size_t ws_size,
                              hipStream_t stream) {
    const float* x   = (const float*)d_in[0];
    const float* ef  = (const float*)d_in[1];
    const int*   src = (const int*)d_in[2];
    const int*   dst = (const int*)d_in[3];
    const float* mW1 = (const float*)d_in[4];
    const float* mb1 = (const float*)d_in[5];
    const float* mW2 = (const float*)d_in[6];
    const float* mb2 = (const float*)d_in[7];
    const float* uW1 = (const float*)d_in[8];
    const float* ub1 = (const float*)d_in[9];
    const float* uW2 = (const float*)d_in[10];
    const float* ub2 = (const float*)d_in[11];

    float*    out  = (float*)d_out;
    unsigned* rkey = (unsigned*)d_out;  // 50000*64 u32 = 12.8 MB

    // ws: part1 u32[E] | dsf u64[E] | bcnt u32[PB*NB] (scanned in place) |
    //     tot u32[256] | boffG u32[256] | xw f32[NVT*16] | h16 u32[E*8]
    unsigned* part1v = (unsigned*)d_ws;
    unsigned long long* dsf = (unsigned long long*)(part1v + N_EDGES);
    unsigned* bcnt   = (unsigned*)(dsf + N_EDGES);
    unsigned* tot    = bcnt + (size_t)PB * NB;
    unsigned* boffG  = tot + 256;
    float*    xw     = (float*)(boffG + 256);
    unsigned* h16    = (unsigned*)(xw + (size_t)NVT * 16);
    const size_t T1_NEEDED =
        (size_t)((char*)(h16 + (size_t)N_EDGES * 8) - (char*)d_ws);

    if (ws_size >= T1_NEEDED) {
        hipLaunchKernelGGL(chist_xw_kernel, dim3(PB),   dim3(256), 0, stream,
                           dst, bcnt, x, mW1, mb1, xw);
        hipLaunchKernelGGL(cscanA_kernel,   dim3(NB),   dim3(256), 0, stream,
                           bcnt, tot);
        hipLaunchKernelGGL(cscanB_kernel,   dim3(1),    dim3(256), 0, stream,
                           tot, boffG);
        hipLaunchKernelGGL(hcomp_kernel,    dim3(3125), dim3(256), 0, stream,
                           ef, src, xw, mW1, rkey, h16);
        hipLaunchKernelGGL(part1_kernel,    dim3(PB),   dim3(256), 0, stream,
                           dst, bcnt, boffG, part1v);
        hipLaunchKernelGGL(part2_kernel,    dim3(NB),   dim3(256), 0, stream,
                           part1v, boffG, tot, dsf);
        hipLaunchKernelGGL(edge_h16_kernel, dim3(3125), dim3(256), 0, stream,
                           h16, dsf, mW2, mb2, rkey);
    } else {
        hipLaunchKernelGGL(init0_kernel, dim3(3125), dim3(256), 0, stream, rkey);
        hipLaunchKernelGGL(edge_kernel, dim3(12500), dim3(64), 0, stream,
                           x, ef, src, dst, mW1, mb1, mW2, mb2, rkey);
    }

    hipLaunchKernelGGL(node4_kernel, dim3((N_NODES + 63) / 64), dim3(256), 0, stream,
                       x, rkey, uW1, ub1, uW2, ub2, out);
}

// Round 16
// 125.923 us; speedup vs baseline: 1.4192x; 1.4192x over previous
//
#include <hip/hip_runtime.h>
#include <hip/hip_fp16.h>

#define N_NODES 50000
#define N_EDGES 800000
// D_FEAT=64, D_EDGE=16, D_HID=16, D_MSG=64, D_OUT=64

#define NB   196    // coarse buckets of 256 nodes (196*256 = 50176)
#define PB   256    // chist/part1 blocks
#define EPB  3125   // edges per block (256*3125 = 800000 exact)
#define PIT  13     // ceil(3125/256)
#define CAP2 4608   // part2 LDS stage capacity (mean 4081, +8 sigma)
#define NVT  50176  // padded node count

__device__ __forceinline__ unsigned fkey(float f) {
    unsigned u = __float_as_uint(f);
    return (u & 0x80000000u) ? ~u : (u | 0x80000000u);
}
#define KEY_NEG_INF 0x007FFFFFu

__device__ __forceinline__ void wave_lds_fence() {
    asm volatile("s_waitcnt lgkmcnt(0)" ::: "memory");
    __builtin_amdgcn_sched_barrier(0);
}

// block-wide exclusive scan of 256 values (one per thread). Uniform call only.
__device__ __forceinline__ unsigned block_exscan256(unsigned v, unsigned* wsum,
                                                    unsigned* chunkTot) {
    const int t = threadIdx.x, lane = t & 63, w = t >> 6;
    unsigned inc = v;
#pragma unroll
    for (int d = 1; d < 64; d <<= 1) {
        unsigned n = __shfl_up(inc, d, 64);
        if (lane >= d) inc += n;
    }
    if (lane == 63) wsum[w] = inc;
    __syncthreads();
    unsigned woff = 0;
#pragma unroll
    for (int i = 0; i < 3; ++i) if (i < w) woff += wsum[i];
    if (chunkTot && t == 255) *chunkTot = woff + inc;
    __syncthreads();
    return woff + inc - v;
}

// ---------------- chist + xw ------------------------------------------------
__global__ __launch_bounds__(256) void chist_xw_kernel(
    const int* __restrict__ dst, unsigned* __restrict__ bcnt,
    const float* __restrict__ x, const float* __restrict__ W1,
    const float* __restrict__ b1, float* __restrict__ xw)
{
    __shared__ unsigned lh[NB];
    const int t = threadIdx.x, b = blockIdx.x;
    if (t < NB) lh[t] = 0u;
    __syncthreads();
    const int e0 = b * EPB;
#pragma unroll
    for (int it = 0; it < PIT; ++it) {
        const int i = it * 256 + t;
        if (i < EPB) atomicAdd(&lh[(unsigned)dst[e0 + i] >> 8], 1u);
    }
    __syncthreads();
    if (t < NB) bcnt[(size_t)b * NB + t] = lh[t];

    if (b < 196) {
        const int v = b * 256 + t;
        if (v < N_NODES) {
            float acc[16];
#pragma unroll
            for (int k = 0; k < 16; ++k) acc[k] = b1[k];
            const float4* xp = reinterpret_cast<const float4*>(x) + (size_t)v * 16;
#pragma unroll
            for (int c = 0; c < 16; ++c) {
                float4 tv = xp[c];
                const float xv[4] = {tv.x, tv.y, tv.z, tv.w};
#pragma unroll
                for (int q = 0; q < 4; ++q) {
                    const int row = 16 + 4 * c + q;
#pragma unroll
                    for (int k = 0; k < 16; ++k)
                        acc[k] = fmaf(xv[q], W1[row * 16 + k], acc[k]);
                }
            }
            float4* op = reinterpret_cast<float4*>(xw) + (size_t)v * 4;
#pragma unroll
            for (int c = 0; c < 4; ++c) {
                float4 o; o.x = acc[4*c]; o.y = acc[4*c+1]; o.z = acc[4*c+2]; o.w = acc[4*c+3];
                op[c] = o;
            }
        }
    }
}

// ---------------- cscanA: in-place exscan of each bucket column ------------
__global__ __launch_bounds__(256) void cscanA_kernel(unsigned* __restrict__ bcnt,
                                                     unsigned* __restrict__ tot) {
    __shared__ unsigned wsum[4];
    const int t = threadIdx.x, bu = blockIdx.x;   // PB == 256: one chunk
    const unsigned v = bcnt[(size_t)t * NB + bu];
    const unsigned excl = block_exscan256(v, wsum, nullptr);
    bcnt[(size_t)t * NB + bu] = excl;
    if (t == 255) tot[bu] = excl + v;
}

// ---------------- cscanB: boffG = exscan(tot[196]) -------------------------
__global__ __launch_bounds__(256) void cscanB_kernel(const unsigned* __restrict__ tot,
                                                     unsigned* __restrict__ boffG) {
    __shared__ unsigned wsum[4];
    const int t = threadIdx.x;
    const unsigned v = (t < NB) ? tot[t] : 0u;
    const unsigned excl = block_exscan256(v, wsum, nullptr);
    if (t < NB) boffG[t] = excl;
}

// ---------------- hcomp: h16 + rkey init -----------------------------------
__global__ __launch_bounds__(256) void hcomp_kernel(
    const float* __restrict__ ef, const int* __restrict__ src,
    const float* __restrict__ xw, const float* __restrict__ W1,
    unsigned* __restrict__ rkey, unsigned* __restrict__ h16)
{
    const int e = blockIdx.x * 256 + threadIdx.x;  // 3125*256 = 800000 exact
    reinterpret_cast<uint4*>(rkey)[e] =
        make_uint4(KEY_NEG_INF, KEY_NEG_INF, KEY_NEG_INF, KEY_NEG_INF);

    float in[16];
    const float4* efp = reinterpret_cast<const float4*>(ef) + (size_t)e * 4;
#pragma unroll
    for (int c = 0; c < 4; ++c) {
        float4 tv = efp[c];
        in[4*c+0]=tv.x; in[4*c+1]=tv.y; in[4*c+2]=tv.z; in[4*c+3]=tv.w;
    }
    const int s = src[e];
    float h[16];
    const float4* xp = reinterpret_cast<const float4*>(xw) + (size_t)s * 4;
#pragma unroll
    for (int c = 0; c < 4; ++c) {
        float4 tv = xp[c];
        h[4*c+0]=tv.x; h[4*c+1]=tv.y; h[4*c+2]=tv.z; h[4*c+3]=tv.w;
    }
#pragma unroll
    for (int i = 0; i < 16; ++i)
#pragma unroll
        for (int k = 0; k < 16; ++k)
            h[k] = fmaf(in[i], W1[i*16 + k], h[k]);
    unsigned wds[8];
#pragma unroll
    for (int k = 0; k < 8; ++k) {
        __half2 t2 = __floats2half2_rn(fmaxf(h[2*k], 0.0f), fmaxf(h[2*k+1], 0.0f));
        wds[k] = *reinterpret_cast<unsigned*>(&t2);
    }
    uint4* hp = reinterpret_cast<uint4*>(h16) + (size_t)e * 2;
    hp[0] = make_uint4(wds[0], wds[1], wds[2], wds[3]);
    hp[1] = make_uint4(wds[4], wds[5], wds[6], wds[7]);
}

// ---------------- part1: coarse partition, payload (nloc8<<20)|e -----------
__global__ __launch_bounds__(256) void part1_kernel(
    const int* __restrict__ dst, const unsigned* __restrict__ gstart,
    const unsigned* __restrict__ boffG, unsigned* __restrict__ part1)
{
    __shared__ unsigned stV[EPB];            // 12.5 KB
    __shared__ unsigned char stB[EPB];       // 3.1 KB
    __shared__ unsigned lh[NB], lstart[NB], lc[NB], gs[NB];
    __shared__ unsigned wsum[4];
    const int t = threadIdx.x, b = blockIdx.x;
    if (t < NB) lh[t] = 0u;
    __syncthreads();
    const int e0 = b * EPB;
#pragma unroll
    for (int it = 0; it < PIT; ++it) {
        const int i = it * 256 + t;
        if (i < EPB) atomicAdd(&lh[(unsigned)dst[e0 + i] >> 8], 1u);
    }
    __syncthreads();
    {
        const unsigned v = (t < NB) ? lh[t] : 0u;
        const unsigned excl = block_exscan256(v, wsum, nullptr);
        if (t < NB) {
            lstart[t] = excl;
            lc[t]     = excl;
            gs[t]     = gstart[(size_t)b * NB + t] + boffG[t];
        }
    }
    __syncthreads();
#pragma unroll
    for (int it = 0; it < PIT; ++it) {
        const int i = it * 256 + t;
        if (i < EPB) {
            const int e = e0 + i;
            const unsigned d = (unsigned)dst[e];
            const unsigned bkt = d >> 8;
            const unsigned p = atomicAdd(&lc[bkt], 1u);
            stV[p] = ((d & 255u) << 20) | (unsigned)e;
            stB[p] = (unsigned char)bkt;
        }
    }
    __syncthreads();
#pragma unroll
    for (int it = 0; it < PIT; ++it) {
        const int i = it * 256 + t;
        if (i < EPB) {
            const unsigned bkt = stB[i];
            part1[gs[bkt] + ((unsigned)i - lstart[bkt])] = stV[i];
        }
    }
}

// ---------------- part2: per-node order, emit u64 (dst<<32)|e --------------
__global__ __launch_bounds__(256) void part2_kernel(
    const unsigned* __restrict__ part1,
    const unsigned* __restrict__ boffG, const unsigned* __restrict__ tot,
    unsigned long long* __restrict__ dsf)
{
    __shared__ unsigned long long stE[CAP2];  // 36.9 KB
    __shared__ unsigned fh[256], fstart[256], fcur[256];
    __shared__ unsigned wsum[4];
    const int t = threadIdx.x, b = blockIdx.x;
    const unsigned gb = boffG[b], cnt = tot[b];
    fh[t] = 0u; fcur[t] = 0u;
    __syncthreads();
    const int iters = (int)((cnt + 255u) >> 8);
    for (int it = 0; it < iters; ++it) {
        const unsigned i = (unsigned)it * 256u + (unsigned)t;
        if (i < cnt) atomicAdd(&fh[part1[gb + i] >> 20], 1u);
    }
    __syncthreads();
    {
        const unsigned v = fh[t];
        fstart[t] = block_exscan256(v, wsum, nullptr);
    }
    __syncthreads();
    for (int it = 0; it < iters; ++it) {
        const unsigned i = (unsigned)it * 256u + (unsigned)t;
        if (i < cnt) {
            const unsigned pv = part1[gb + i];
            const unsigned nloc = pv >> 20;
            const unsigned e = pv & 0xFFFFFu;
            const unsigned pos = fstart[nloc] + atomicAdd(&fcur[nloc], 1u);
            const unsigned long long val =
                ((unsigned long long)((unsigned)b * 256u + nloc) << 32) | e;
            if (pos < CAP2) stE[pos] = val;
            else            dsf[gb + pos] = val;   // statistically unreachable
        }
    }
    __syncthreads();
    const unsigned lim = (cnt < CAP2) ? cnt : CAP2;
    for (int it = 0; it < iters; ++it) {
        const unsigned i = (unsigned)it * 256u + (unsigned)t;
        if (i < lim) dsf[gb + i] = stE[i];   // perfectly sequential
    }
}

// ---------------- edge_h16 (r7 verbatim, measured 44.7us) ------------------
__global__ __launch_bounds__(256) void edge_h16_kernel(
    const unsigned* __restrict__ h16,
    const unsigned long long* __restrict__ ds,
    const float* __restrict__ W2, const float* __restrict__ b2,
    unsigned* __restrict__ rkey)
{
    const int lane = threadIdx.x & 63;
    const int w    = threadIdx.x >> 6;
    const int wave = blockIdx.x * 4 + w;
    const int base = wave * 64;
    const int slot = base + lane;

    __shared__ unsigned mld[4][64][17];
    __shared__ int      dldA[4][66];
    int* dld = &dldA[w][1];

    const unsigned long long pv = ds[slot];
    const int e = (int)(unsigned)pv;
    const int d = (int)(pv >> 32);
    dld[lane] = d;
    if (lane == 0)  dld[-1] = (base == 0) ? -1 : (int)(ds[base - 1] >> 32);
    if (lane == 63) dld[64] = (base + 64 >= N_EDGES) ? -1 : (int)(ds[base + 64] >> 32);

    // ---- gather h (32 B random from 25.6 MB) ----
    float h[16];
    {
        const uint4* hp = reinterpret_cast<const uint4*>(h16) + (size_t)e * 2;
        uint4 A = hp[0], B = hp[1];
        unsigned wd[8] = {A.x, A.y, A.z, A.w, B.x, B.y, B.z, B.w};
#pragma unroll
        for (int k = 0; k < 8; ++k) {
            __half2 t2 = *reinterpret_cast<const __half2*>(&wd[k]);
            float2 f = __half22float2(t2);
            h[2*k] = f.x; h[2*k+1] = f.y;
        }
    }

    const int q  = lane >> 4;
    const int jj = lane & 15;

#pragma unroll
    for (int j0 = 0; j0 < 64; j0 += 16) {
        float m[16];
#pragma unroll
        for (int t = 0; t < 16; ++t) m[t] = b2[j0 + t];
#pragma unroll
        for (int k = 0; k < 16; ++k)
#pragma unroll
            for (int t = 0; t < 16; ++t)
                m[t] = fmaf(h[k], W2[k*64 + j0 + t], m[t]);

        wave_lds_fence();
#pragma unroll
        for (int t = 0; t < 16; ++t) mld[w][lane][t] = fkey(m[t]);
        wave_lds_fence();

        const int s0 = q * 16;
        unsigned run = KEY_NEG_INF;
        int  dprev = dld[s0 - 1];
        bool phead = (dld[s0] != dprev);
        dprev = dld[s0];
        run = mld[w][s0][jj];
#pragma unroll
        for (int i = 1; i < 16; ++i) {
            const int ss = s0 + i;
            const int dsv = dld[ss];
            if (dsv != dprev) {
                unsigned* addr = &rkey[((size_t)dprev << 6) + (unsigned)(j0 + jj)];
                if (phead) *addr = run;
                else       atomicMax(addr, run);
                run = KEY_NEG_INF;
                phead = true;
            }
            run = max(run, mld[w][ss][jj]);
            dprev = dsv;
        }
        const bool ptail = (dld[s0 + 16] != dprev);
        unsigned* addr = &rkey[((size_t)dprev << 6) + (unsigned)(j0 + jj)];
        if (phead && ptail) *addr = run;
        else                atomicMax(addr, run);
    }
}

// ---------------- node4 v2: 4 threads/node + LDS-staged weights ------------
// r15's node4 was 79us at VALUBusy 4.9%: lane-dependent weight rows demoted
// the weight path from s_load broadcast to per-lane VMEM (512 loads/thread
// latency chain). Fix: stage uW1 (8KB) + uW2 (4KB) in LDS once per block;
// divergent rows become ds_read_b128 (<=4 distinct rows/wave, broadcast).
// Store pattern kept: 4-lane group writes one contiguous 256B burst.
// rkey/out alias d_out: each group reads only its node's row before writing.
__global__ __launch_bounds__(256) void node4_kernel(
    const float* __restrict__ x, const unsigned* rkey,
    const float* __restrict__ W1, const float* __restrict__ b1,
    const float* __restrict__ W2, const float* __restrict__ b2,
    float* out)
{
    __shared__ float w1s[128 * 16];   // 8 KB
    __shared__ float w2s[16 * 64];    // 4 KB
    const int tid = threadIdx.x;
    {   // coalesced weight staging
        const float4* s1 = reinterpret_cast<const float4*>(W1);
        float4* d1 = reinterpret_cast<float4*>(w1s);
        d1[tid]       = s1[tid];        // 512 float4 total
        d1[tid + 256] = s1[tid + 256];
        const float4* s2 = reinterpret_cast<const float4*>(W2);
        reinterpret_cast<float4*>(w2s)[tid] = s2[tid];  // 256 float4
    }
    __syncthreads();

    const int g = tid >> 2;        // node within block, 0..63
    const int q = tid & 3;         // quarter
    const int v = blockIdx.x * 64 + g;
    if (v >= N_NODES) return;      // whole 4-lane group exits together

    // x rows [q*16, q*16+16)
    float xv[16];
    const float4* xp = reinterpret_cast<const float4*>(x) + (size_t)v * 16 + q * 4;
#pragma unroll
    for (int c = 0; c < 4; ++c) {
        float4 tv = xp[c];
        xv[4*c+0]=tv.x; xv[4*c+1]=tv.y; xv[4*c+2]=tv.z; xv[4*c+3]=tv.w;
    }
    // r rows [q*16, q*16+16) decoded from rkey
    float rv[16];
    const uint4* rp = reinterpret_cast<const uint4*>(rkey) + (size_t)v * 16 + q * 4;
#pragma unroll
    for (int c = 0; c < 4; ++c) {
        uint4 tv = rp[c];
        unsigned ks[4] = {tv.x, tv.y, tv.z, tv.w};
#pragma unroll
        for (int qq = 0; qq < 4; ++qq) {
            unsigned k = ks[qq];
            unsigned u = (k & 0x80000000u) ? (k ^ 0x80000000u) : ~k;
            float f = __uint_as_float(u);
            if (!(f >= -3.402823466e38f && f <= 3.402823466e38f)) f = 0.0f;
            rv[4*c + qq] = f;
        }
    }

    // partial h2 over this lane's 32 rows (weights from LDS)
    float h2[16];
#pragma unroll
    for (int k = 0; k < 16; ++k) h2[k] = 0.0f;
#pragma unroll
    for (int rr = 0; rr < 16; ++rr) {
        const int row = q * 16 + rr;
        const float4* wr = reinterpret_cast<const float4*>(&w1s[row * 16]);
        float4 w0 = wr[0], w1v = wr[1], w2v = wr[2], w3 = wr[3];
        const float wf[16] = {w0.x,w0.y,w0.z,w0.w, w1v.x,w1v.y,w1v.z,w1v.w,
                              w2v.x,w2v.y,w2v.z,w2v.w, w3.x,w3.y,w3.z,w3.w};
#pragma unroll
        for (int k = 0; k < 16; ++k) h2[k] = fmaf(xv[rr], wf[k], h2[k]);
    }
#pragma unroll
    for (int rr = 0; rr < 16; ++rr) {
        const int row = 64 + q * 16 + rr;
        const float4* wr = reinterpret_cast<const float4*>(&w1s[row * 16]);
        float4 w0 = wr[0], w1v = wr[1], w2v = wr[2], w3 = wr[3];
        const float wf[16] = {w0.x,w0.y,w0.z,w0.w, w1v.x,w1v.y,w1v.z,w1v.w,
                              w2v.x,w2v.y,w2v.z,w2v.w, w3.x,w3.y,w3.z,w3.w};
#pragma unroll
        for (int k = 0; k < 16; ++k) h2[k] = fmaf(rv[rr], wf[k], h2[k]);
    }
    // butterfly over the 4-lane group (masks 1,2 stay within group)
#pragma unroll
    for (int mk = 1; mk <= 2; mk <<= 1)
#pragma unroll
        for (int k = 0; k < 16; ++k)
            h2[k] += __shfl_xor(h2[k], mk, 64);
#pragma unroll
    for (int k = 0; k < 16; ++k) h2[k] = fmaxf(h2[k] + b1[k], 0.0f);

    // out cols [q*16, +16): 4-lane group writes 256B contiguous
    float* op = out + (size_t)v * 64 + q * 16;
#pragma unroll
    for (int c = 0; c < 4; ++c) {
        float oo[4] = {0.0f, 0.0f, 0.0f, 0.0f};
#pragma unroll
        for (int k = 0; k < 16; ++k) {
            const float4 wv = *reinterpret_cast<const float4*>(
                &w2s[k * 64 + q * 16 + 4 * c]);
            oo[0] = fmaf(h2[k], wv.x, oo[0]);
            oo[1] = fmaf(h2[k], wv.y, oo[1]);
            oo[2] = fmaf(h2[k], wv.z, oo[2]);
            oo[3] = fmaf(h2[k], wv.w, oo[3]);
        }
        float4 o;
        o.x = oo[0] + b2[q*16 + 4*c + 0];
        o.y = oo[1] + b2[q*16 + 4*c + 1];
        o.z = oo[2] + b2[q*16 + 4*c + 2];
        o.w = oo[3] + b2[q*16 + 4*c + 3];
        reinterpret_cast<float4*>(op)[c] = o;
    }
}

// =================== fallback tier (tiny ws): direct atomics ===============
__global__ __launch_bounds__(256) void init0_kernel(unsigned* __restrict__ rkey) {
    const int i = blockIdx.x * 256 + threadIdx.x;
    reinterpret_cast<uint4*>(rkey)[i] =
        make_uint4(KEY_NEG_INF, KEY_NEG_INF, KEY_NEG_INF, KEY_NEG_INF);
}

__global__ __launch_bounds__(64) void edge_kernel(
    const float* __restrict__ x, const float* __restrict__ ef,
    const int* __restrict__ src, const int* __restrict__ dst,
    const float* __restrict__ W1, const float* __restrict__ b1,
    const float* __restrict__ W2, const float* __restrict__ b2,
    unsigned* __restrict__ rkey)
{
    const int lane = threadIdx.x;
    const int e    = blockIdx.x * 64 + lane;
    __shared__ unsigned mld[64][17];
    __shared__ int      dld[64];
    float in[80];
    const float4* efp = reinterpret_cast<const float4*>(ef) + (size_t)e * 4;
#pragma unroll
    for (int c = 0; c < 4; ++c) {
        float4 tv = efp[c];
        in[4*c+0]=tv.x; in[4*c+1]=tv.y; in[4*c+2]=tv.z; in[4*c+3]=tv.w;
    }
    const int s = src[e];
    dld[lane] = dst[e];
    const float4* xp = reinterpret_cast<const float4*>(x) + (size_t)s * 16;
#pragma unroll
    for (int c = 0; c < 16; ++c) {
        float4 tv = xp[c];
        in[16+4*c+0]=tv.x; in[16+4*c+1]=tv.y; in[16+4*c+2]=tv.z; in[16+4*c+3]=tv.w;
    }
    float h[16];
#pragma unroll
    for (int k = 0; k < 16; ++k) h[k] = b1[k];
#pragma unroll
    for (int i = 0; i < 80; ++i)
#pragma unroll
        for (int k = 0; k < 16; ++k)
            h[k] = fmaf(in[i], W1[i*16 + k], h[k]);
#pragma unroll
    for (int k = 0; k < 16; ++k) h[k] = fmaxf(h[k], 0.0f);
    const int er = lane >> 4, jj = lane & 15;
#pragma unroll
    for (int j0 = 0; j0 < 64; j0 += 16) {
        float m[16];
#pragma unroll
        for (int t = 0; t < 16; ++t) m[t] = b2[j0 + t];
#pragma unroll
        for (int k = 0; k < 16; ++k)
#pragma unroll
            for (int t = 0; t < 16; ++t)
                m[t] = fmaf(h[k], W2[k*64 + j0 + t], m[t]);
        wave_lds_fence();
#pragma unroll
        for (int t = 0; t < 16; ++t) mld[lane][t] = fkey(m[t]);
        wave_lds_fence();
#pragma unroll
        for (int eg = 0; eg < 16; ++eg) {
            const int ee = (eg << 2) | er;
            atomicMax(&rkey[((size_t)dld[ee] << 6) + (unsigned)(j0 + jj)],
                      mld[ee][jj]);
        }
    }
}

// fallback node kernel (uniform weights -> s_load; known 45us, correct)
__global__ __launch_bounds__(256) void node_kernel(
    const float* __restrict__ x, const unsigned* rkey,
    const float* __restrict__ W1, const float* __restrict__ b1,
    const float* __restrict__ W2, const float* __restrict__ b2,
    float* out)
{
    const int v = blockIdx.x * 256 + threadIdx.x;
    if (v >= N_NODES) return;
    float in[128];
    const float4* xp = reinterpret_cast<const float4*>(x) + (size_t)v * 16;
#pragma unroll
    for (int c = 0; c < 16; ++c) {
        float4 tv = xp[c];
        in[4*c+0]=tv.x; in[4*c+1]=tv.y; in[4*c+2]=tv.z; in[4*c+3]=tv.w;
    }
    const uint4* rp = reinterpret_cast<const uint4*>(rkey) + (size_t)v * 16;
#pragma unroll
    for (int c = 0; c < 16; ++c) {
        uint4 tv = rp[c];
        unsigned ks[4] = {tv.x, tv.y, tv.z, tv.w};
#pragma unroll
        for (int qq = 0; qq < 4; ++qq) {
            unsigned k = ks[qq];
            unsigned u = (k & 0x80000000u) ? (k ^ 0x80000000u) : ~k;
            float f = __uint_as_float(u);
            if (!(f >= -3.402823466e38f && f <= 3.402823466e38f)) f = 0.0f;
            in[64 + 4*c + qq] = f;
        }
    }
    float h[16];
#pragma unroll
    for (int k = 0; k < 16; ++k) h[k] = b1[k];
#pragma unroll
    for (int i = 0; i < 128; ++i)
#pragma unroll
        for (int k = 0; k < 16; ++k)
            h[k] = fmaf(in[i], W1[i*16 + k], h[k]);
#pragma unroll
    for (int k = 0; k < 16; ++k) h[k] = fmaxf(h[k], 0.0f);
    float* op = out + (size_t)v * 64;
#pragma unroll
    for (int c = 0; c < 16; ++c) {
        float oo[4];
#pragma unroll
        for (int qq = 0; qq < 4; ++qq) {
            float a = b2[4*c + qq];
#pragma unroll
            for (int k = 0; k < 16; ++k)
                a = fmaf(h[k], W2[k*64 + 4*c + qq], a);
            oo[qq] = a;
        }
        float4 o; o.x=oo[0]; o.y=oo[1]; o.z=oo[2]; o.w=oo[3];
        reinterpret_cast<float4*>(op)[c] = o;
    }
}

extern "C" void kernel_launch(void* const* d_in, const int* in_sizes, int n_in,
                              void* d_out, int out_size, void* d_ws, size_t ws_size,
                              hipStream_t stream) {
    const float* x   = (const float*)d_in[0];
    const float* ef  = (const float*)d_in[1];
    const int*   src = (const int*)d_in[2];
    const int*   dst = (const int*)d_in[3];
    const float* mW1 = (const float*)d_in[4];
    const float* mb1 = (const float*)d_in[5];
    const float* mW2 = (const float*)d_in[6];
    const float* mb2 = (const float*)d_in[7];
    const float* uW1 = (const float*)d_in[8];
    const float* ub1 = (const float*)d_in[9];
    const float* uW2 = (const float*)d_in[10];
    const float* ub2 = (const float*)d_in[11];

    float*    out  = (float*)d_out;
    unsigned* rkey = (unsigned*)d_out;  // 50000*64 u32 = 12.8 MB

    // ws: part1 u32[E] | dsf u64[E] | bcnt u32[PB*NB] (scanned in place) |
    //     tot u32[256] | boffG u32[256] | xw f32[NVT*16] | h16 u32[E*8]
    unsigned* part1v = (unsigned*)d_ws;
    unsigned long long* dsf = (unsigned long long*)(part1v + N_EDGES);
    unsigned* bcnt   = (unsigned*)(dsf + N_EDGES);
    unsigned* tot    = bcnt + (size_t)PB * NB;
    unsigned* boffG  = tot + 256;
    float*    xw     = (float*)(boffG + 256);
    unsigned* h16    = (unsigned*)(xw + (size_t)NVT * 16);
    const size_t T1_NEEDED =
        (size_t)((char*)(h16 + (size_t)N_EDGES * 8) - (char*)d_ws);

    if (ws_size >= T1_NEEDED) {
        hipLaunchKernelGGL(chist_xw_kernel, dim3(PB),   dim3(256), 0, stream,
                           dst, bcnt, x, mW1, mb1, xw);
        hipLaunchKernelGGL(cscanA_kernel,   dim3(NB),   dim3(256), 0, stream,
                           bcnt, tot);
        hipLaunchKernelGGL(cscanB_kernel,   dim3(1),    dim3(256), 0, stream,
                           tot, boffG);
        hipLaunchKernelGGL(hcomp_kernel,    dim3(3125), dim3(256), 0, stream,
                           ef, src, xw, mW1, rkey, h16);
        hipLaunchKernelGGL(part1_kernel,    dim3(PB),   dim3(256), 0, stream,
                           dst, bcnt, boffG, part1v);
        hipLaunchKernelGGL(part2_kernel,    dim3(NB),   dim3(256), 0, stream,
                           part1v, boffG, tot, dsf);
        hipLaunchKernelGGL(edge_h16_kernel, dim3(3125), dim3(256), 0, stream,
                           h16, dsf, mW2, mb2, rkey);
        hipLaunchKernelGGL(node4_kernel, dim3((N_NODES + 63) / 64), dim3(256), 0, stream,
                           x, rkey, uW1, ub1, uW2, ub2, out);
    } else {
        hipLaunchKernelGGL(init0_kernel, dim3(3125), dim3(256), 0, stream, rkey);
        hipLaunchKernelGGL(edge_kernel, dim3(12500), dim3(64), 0, stream,
                           x, ef, src, dst, mW1, mb1, mW2, mb2, rkey);
        hipLaunchKernelGGL(node_kernel, dim3((N_NODES + 255) / 256), dim3(256), 0, stream,
                           x, rkey, uW1, ub1, uW2, ub2, out);
    }
}